// Round 1
// baseline (315.946 us; speedup 1.0000x reference)
//
#include <hip/hip_runtime.h>

// Problem constants (fixed by reference setup_inputs)
#define NB 32
#define NC 128
#define NH 63
#define NW 63
#define KK 5
#define ST 2
#define OH 30          // (63-5)/2+1
#define OW 30
#define NL (OH*OW)     // 900
#define PSTRIDE 132    // padded LDS c-stride (128 + 4)

__global__ void init_tops(float* tops) {
    int t = threadIdx.x;
    if (t < NB) tops[t] = 0.0f;
}

__global__ __launch_bounds__(128) void tile_kernel(const float* __restrict__ f,
                                                   float* __restrict__ tops) {
    const int blk = blockIdx.x;
    const int b  = blk / NL;
    const int l  = blk % NL;
    const int oi = l / OW;
    const int oj = l % OW;
    const int y0 = oi * ST, x0 = oj * ST;

    __shared__ float patch[25 * PSTRIDE];  // [pos][c], padded
    __shared__ float dots[25 * 26];        // Gram, padded stride 26
    __shared__ float norms[25];
    __shared__ float svals[25];

    const int t = threadIdx.x;
    const float* fb = f + (size_t)b * NC * NH * NW;

    // ---- stage patch: thread t owns channel c=t, loads all 25 positions ----
    {
        const int c = t;  // 128 threads == 128 channels
        const float* fc = fb + (size_t)c * (NH * NW);
        #pragma unroll
        for (int p = 0; p < 25; ++p) {
            const int y = y0 + p / 5;
            const int x = x0 + p % 5;
            patch[p * PSTRIDE + c] = fc[y * NW + x];
        }
    }
    __syncthreads();

    // ---- Gram: 15 symmetric 5x5 pair-blocks x 8 c-chunks = 120 threads ----
    if (t < 120) {
        const int pb = t >> 3;    // pair-block 0..14
        const int ck = t & 7;     // c-chunk 0..7 (16 channels each)
        int p5 = 0, rem = pb;
        while (rem >= 5 - p5) { rem -= 5 - p5; ++p5; }
        const int q5 = p5 + rem;  // p5 <= q5

        float acc[5][5];
        #pragma unroll
        for (int i = 0; i < 5; ++i)
            #pragma unroll
            for (int j = 0; j < 5; ++j) acc[i][j] = 0.0f;

        const int cbase = ck * 16;
        #pragma unroll
        for (int c4 = 0; c4 < 4; ++c4) {
            float4 av[5], bv[5];
            #pragma unroll
            for (int i = 0; i < 5; ++i)
                av[i] = *(const float4*)&patch[(p5 * 5 + i) * PSTRIDE + cbase + c4 * 4];
            #pragma unroll
            for (int j = 0; j < 5; ++j)
                bv[j] = *(const float4*)&patch[(q5 * 5 + j) * PSTRIDE + cbase + c4 * 4];
            #pragma unroll
            for (int i = 0; i < 5; ++i)
                #pragma unroll
                for (int j = 0; j < 5; ++j) {
                    acc[i][j] += av[i].x * bv[j].x + av[i].y * bv[j].y
                               + av[i].z * bv[j].z + av[i].w * bv[j].w;
                }
        }
        // reduce over the 8 c-chunk lanes (groups of 8, 8-aligned within wave)
        #pragma unroll
        for (int i = 0; i < 5; ++i)
            #pragma unroll
            for (int j = 0; j < 5; ++j) {
                float v = acc[i][j];
                v += __shfl_xor(v, 1);
                v += __shfl_xor(v, 2);
                v += __shfl_xor(v, 4);
                acc[i][j] = v;
            }
        if (ck == 0) {
            #pragma unroll
            for (int i = 0; i < 5; ++i)
                #pragma unroll
                for (int j = 0; j < 5; ++j) {
                    const int p = p5 * 5 + i, q = q5 * 5 + j;
                    dots[p * 26 + q] = acc[i][j];
                    if (p5 != q5) dots[q * 26 + p] = acc[i][j];
                }
        }
    }
    __syncthreads();

    // ---- cosine-distance mean over q, per p ----
    if (t < 25) norms[t] = sqrtf(dots[t * 26 + t]);
    __syncthreads();
    if (t < 25) {
        const float np_ = norms[t];
        float s = 0.0f;
        #pragma unroll
        for (int q = 0; q < 25; ++q) {
            const float denom = fmaxf(np_ * norms[q], 1e-6f);
            s += 1.0f - dots[t * 26 + q] / denom;
        }
        svals[t] = s * (1.0f / 25.0f);
    }
    __syncthreads();

    // ---- max over p, then atomic max over L into per-b slot ----
    if (t == 0) {
        float m = svals[0];
        #pragma unroll
        for (int p = 1; p < 25; ++p) m = fmaxf(m, svals[p]);
        // values are >= 0, so int-compare == float-compare
        atomicMax((int*)&tops[b], __float_as_int(m));
    }
}

__global__ void finalize(const float* __restrict__ tops,
                         const int* __restrict__ label,
                         float* __restrict__ out) {
    if (threadIdx.x == 0) {
        float fs = 0.0f, rs = 0.0f, fc = 0.0f, rc = 0.0f;
        for (int b = 0; b < NB; ++b) {
            const float tb = tops[b];
            const float lb = (float)label[b];
            fs += tb * lb;        fc += lb;
            rs += tb * (1.0f - lb); rc += (1.0f - lb);
        }
        const float loss = 1.0f - fs / fc + rs / rc;
        out[0] = fmaxf(loss, 0.0f);
    }
}

extern "C" void kernel_launch(void* const* d_in, const int* in_sizes, int n_in,
                              void* d_out, int out_size, void* d_ws, size_t ws_size,
                              hipStream_t stream) {
    const float* feature = (const float*)d_in[0];
    const int* label     = (const int*)d_in[1];
    float* out  = (float*)d_out;
    float* tops = (float*)d_ws;   // 32 floats of scratch

    init_tops<<<1, 64, 0, stream>>>(tops);
    tile_kernel<<<NB * NL, 128, 0, stream>>>(feature, tops);
    finalize<<<1, 64, 0, stream>>>(tops, label, out);
}